// Round 3
// baseline (1143.312 us; speedup 1.0000x reference)
//
#include <hip/hip_runtime.h>
#include <stdint.h>
#include <math.h>

#define BATCH 131072
#define WS_LO_OFF 65536
#define WS_TN_OFF 131072
#define WS_B_OFF  131080   // 6 x 64 floats: nb1,nb2,ab1,ab2,ob1,ob2

typedef __attribute__((ext_vector_type(8)))  short short8;   // 8 bf16
typedef __attribute__((ext_vector_type(16))) float float16;  // MFMA 32x32 acc

union S8 { short8 s; uint32_t u[4]; };
union F8 { float f[8]; uint32_t u[8]; float4 v4[2]; };

// ---------------- prep: weights -> bf16 hi/lo in B-frag order; biases + |tvec| into ws ----
__global__ __launch_bounds__(256)
void prep_kernel(const float* __restrict__ tvec,
                 const float* __restrict__ nW1, const float* __restrict__ nW2,
                 const float* __restrict__ aW1, const float* __restrict__ aW2,
                 const float* __restrict__ oW1, const float* __restrict__ oW2,
                 const float* __restrict__ nb1, const float* __restrict__ nb2,
                 const float* __restrict__ ab1, const float* __restrict__ ab2,
                 const float* __restrict__ ob1, const float* __restrict__ ob2,
                 char* __restrict__ ws)
{
    const int id = blockIdx.x * 256 + threadIdx.x;
    if (id == 0) {
        float s = 0.f;
        for (int j = 0; j < 64; ++j) s = fmaf(tvec[j], tvec[j], s);
        *(float*)(ws + WS_TN_OFF) = fmaxf(sqrtf(s), 1e-8f);
    }
    if (id < 32768) {
        const float* srcs[8] = { nW1, nW2, aW1, aW1 + 4096, aW2, oW1, oW1 + 4096, oW2 };
        const int u    = id >> 12;
        const int e    = id & 4095;
        const int j    = e & 7;
        const int lane = (e >> 3) & 63;
        const int f    = e >> 9;          // kc*2 + nt
        const int nt   = f & 1, kc = f >> 1;
        const int k    = kc * 16 + (lane >> 5) * 8 + j;
        const int n    = nt * 32 + (lane & 31);
        const float v  = srcs[u][k * 64 + n];
        const uint32_t b  = __float_as_uint(v);
        const uint32_t hb = b & 0xffff0000u;
        const uint32_t lo = __float_as_uint(v - __uint_as_float(hb));
        ((uint16_t*)(ws + u * 8192 + f * 1024 + lane * 16))[j]             = (uint16_t)(b  >> 16);
        ((uint16_t*)(ws + WS_LO_OFF + u * 8192 + f * 1024 + lane * 16))[j] = (uint16_t)(lo >> 16);
    } else if (id < 33152) {
        const int b   = id - 32768;       // 0..383
        const int arr = b >> 6, j = b & 63;
        const float* bp = (arr == 0) ? nb1 : (arr == 1) ? nb2 : (arr == 2) ? ab1
                        : (arr == 3) ? ab2 : (arr == 4) ? ob1 : ob2;
        ((float*)(ws + WS_B_OFF))[b] = bp[j];
    }
}

// ---------------- main kernel: micro-coded 23-pass program ----------------
// cw fields: u(0:2) | g(3:5) | initk(6:7) | toB(8) | epik(9:11) | bid(12:14)
// initk: 0 none, 1 bias->acc, 2 acc=accB, 3 bias->accB
// epik : 0 none, 1 act->S0, 2 raw->S0, 4 reduce(pos), 5 reduce(neg)   (src = toB?accB:acc)
// g    : 0 none, 1..5 seq[:,g-1], 6 pos_target, 7 neg_target
#define OP(u,g,ik,tb,ek,bd) ((u)|((g)<<3)|((ik)<<6)|((tb)<<8)|((ek)<<9)|((bd)<<12))

__global__ __launch_bounds__(256, 4)
void logicnet_mfma(const int* __restrict__ seq, const int* __restrict__ post,
                   const int* __restrict__ negt, const float* __restrict__ E,
                   const float* __restrict__ tvec,
                   const char* __restrict__ ws, float* __restrict__ out)
{
    static const uint32_t PROG[23] = {
        OP(0,2,1,0,1,0),  // n1 : nb1 + NOT_W1 @ gather(s1), act
        OP(1,0,1,0,2,1),  // n1 : nb2 + W2 @ S0, raw            [S0=n1]
        OP(3,0,1,0,0,2),  // i5 : ab1 + aW1hi @ n1
        OP(2,1,0,0,1,0),  //    : += aW1lo @ gather(s0), act
        OP(4,0,1,0,2,3),  // i5 : ab2 + aW2 @ S0, raw           [S0=i5]
        OP(2,0,3,1,0,2),  // i7p: accB = ab1 + aW1lo @ i5
        OP(5,3,1,0,0,4),  // i6 : ob1 + oW1lo @ gather(s2)
        OP(6,4,0,0,1,0),  //    : += oW1hi @ gather(s3), act
        OP(7,0,1,0,2,5),  // i6 : ob2 + oW2 @ S0, raw           [S0=i6]
        OP(3,0,0,1,1,0),  // i7 : accB += aW1hi @ i6, act       [S0=h(i7)]
        OP(4,0,1,0,2,3),  // i7 : ab2 + aW2 @ S0, raw           [S0=i7]
        OP(0,0,1,0,1,0),  // n7 : nb1 ..., act
        OP(1,0,1,0,2,1),  // n7 : nb2 ..., raw                  [S0=n7]
        OP(5,0,1,0,0,4),  // o8 : ob1 + oW1lo @ n7
        OP(6,5,0,0,1,0),  //    : += oW1hi @ gather(s4), act
        OP(7,0,1,0,2,5),  // o8 : ob2 + oW2 @ S0, raw           [S0=out8]
        OP(0,0,1,0,1,0),  // enc: nb1 ..., act
        OP(1,0,1,0,2,1),  // enc: nb2 ..., raw                  [S0=enc]
        OP(5,0,3,1,0,4),  // E  : accB = ob1 + oW1lo @ enc
        OP(6,6,2,0,1,0),  // pos: acc=accB; += oW1hi @ gather(ip), act
        OP(7,0,1,0,4,5),  // pos: ob2 + oW2 @ S0, reduce->out
        OP(6,7,2,0,1,0),  // neg: acc=accB; += oW1hi @ gather(im), act
        OP(7,0,1,0,5,5),  // neg: ob2 + oW2 @ S0, reduce->out+B
    };

    __shared__ uint32_t lds[4 * 2112];     // per-wave slot: 32 rows x stride 66
    const int tid  = threadIdx.x;
    const int wid  = tid >> 6;
    const int lane = tid & 63;
    const int m    = lane & 31;            // batch row in tile / C col
    const int h    = lane >> 5;            // k-half / row-half selector
    const int rowbase = (blockIdx.x * 4 + wid) * 32;
    const int rr   = rowbase + m;
    uint32_t* const stage = &lds[wid * 2112];

    const float  tn  = *(const float*)(ws + WS_TN_OFF);
    const float* wsb = (const float*)(ws + WS_B_OFF);

    float16 acc[2], accB[2];

    // one 64x64 matvec term-set, A streamed from stage, B(weights) from ws
    auto ua = [&](float16* A, int u) {
        const char* wb = ws + u * 8192 + lane * 16;
#pragma unroll
        for (int kc = 0; kc < 4; ++kc) {
            const uint2* p2 = (const uint2*)&stage[m * 66 + kc * 16 + h * 8];
            uint2 a0 = p2[0], a1 = p2[1], a2 = p2[2], a3 = p2[3];
            const uint32_t w0 = a0.x, w1 = a0.y, w2 = a1.x, w3 = a1.y;
            const uint32_t w4 = a2.x, w5 = a2.y, w6 = a3.x, w7 = a3.y;
            S8 xhi, xlo;
            xhi.u[0] = (w0 >> 16) | (w1 & 0xffff0000u);
            xhi.u[1] = (w2 >> 16) | (w3 & 0xffff0000u);
            xhi.u[2] = (w4 >> 16) | (w5 & 0xffff0000u);
            xhi.u[3] = (w6 >> 16) | (w7 & 0xffff0000u);
            xlo.u[0] = (w0 & 0xffffu) | (w1 << 16);
            xlo.u[1] = (w2 & 0xffffu) | (w3 << 16);
            xlo.u[2] = (w4 & 0xffffu) | (w5 << 16);
            xlo.u[3] = (w6 & 0xffffu) | (w7 << 16);
#pragma unroll
            for (int nt = 0; nt < 2; ++nt) {
                const int off = (kc * 2 + nt) * 1024;
                short8 whi = *(const short8*)(wb + off);
                short8 wlo = *(const short8*)(wb + WS_LO_OFF + off);
                A[nt] = __builtin_amdgcn_mfma_f32_32x32x16_bf16(xhi.s, whi, A[nt], 0, 0, 0);
                A[nt] = __builtin_amdgcn_mfma_f32_32x32x16_bf16(xlo.s, whi, A[nt], 0, 0, 0);
                A[nt] = __builtin_amdgcn_mfma_f32_32x32x16_bf16(xhi.s, wlo, A[nt], 0, 0, 0);
            }
        }
    };

    // C-layout -> packed hi|lo into stage (optionally leaky-relu)
    auto epi_store = [&](const float16* A, bool act) {
#pragma unroll
        for (int nt = 0; nt < 2; ++nt) {
            const int c = nt * 32 + m;
#pragma unroll
            for (int g = 0; g < 4; ++g)
#pragma unroll
                for (int q = 0; q < 4; ++q) {
                    const int r = q + 8 * g + 4 * h;
                    float v = A[nt][g * 4 + q];
                    if (act) v = fmaxf(v, 0.01f * v);
                    const uint32_t uu = __float_as_uint(v);
                    const uint32_t hb = uu & 0xffff0000u;
                    const uint32_t lo = __float_as_uint(v - __uint_as_float(hb));
                    stage[r * 66 + c] = hb | (lo >> 16);
                }
        }
    };

    // gather embedding row -> stage (packed), rows = batch tile
    auto gwrite = [&](int g) {
        int idx;
        if (g < 6)      idx = seq[(size_t)rr * 5 + (g - 1)];
        else if (g == 6) idx = post[rr];
        else             idx = negt[rr];
        const float4* e = (const float4*)(E + (size_t)idx * 64 + h * 8);
#pragma unroll
        for (int kc = 0; kc < 4; ++kc) {
            F8 xf8;
            xf8.v4[0] = e[kc * 4];
            xf8.v4[1] = e[kc * 4 + 1];
            uint32_t pk[8];
#pragma unroll
            for (int i = 0; i < 8; ++i) {
                const uint32_t b  = xf8.u[i];
                const uint32_t hb = b & 0xffff0000u;
                const uint32_t lo = __float_as_uint(xf8.f[i] - __uint_as_float(hb));
                pk[i] = hb | (lo >> 16);
            }
            uint2* q = (uint2*)&stage[m * 66 + kc * 16 + h * 8];
            q[0] = make_uint2(pk[0], pk[1]);
            q[1] = make_uint2(pk[2], pk[3]);
            q[2] = make_uint2(pk[4], pk[5]);
            q[3] = make_uint2(pk[6], pk[7]);
        }
    };

    auto epi_reduce = [&](float* outp) {
#pragma unroll
        for (int nt = 0; nt < 2; ++nt) {
            const int c = nt * 32 + m;
#pragma unroll
            for (int g = 0; g < 4; ++g)
#pragma unroll
                for (int q = 0; q < 4; ++q) {
                    const int r = q + 8 * g + 4 * h;
                    stage[r * 66 + c] = __float_as_uint(acc[nt][g * 4 + q]);
                }
        }
        float num = 0.f, ss = 0.f;
        const float* tp = tvec + h * 32;
        const uint32_t* xp = &stage[m * 66 + h * 32];
#pragma unroll
        for (int i = 0; i < 32; i += 2) {
            const float x0 = __uint_as_float(xp[i]);
            const float x1 = __uint_as_float(xp[i + 1]);
            num = fmaf(x0, tp[i], fmaf(x1, tp[i + 1], num));
            ss  = fmaf(x0, x0, fmaf(x1, x1, ss));
        }
        num += __shfl_xor(num, 32, 64);
        ss  += __shfl_xor(ss, 32, 64);
        if (h == 0) outp[m] = num / (fmaxf(sqrtf(ss), 1e-8f) * tn) * 10.0f;
    };

#pragma unroll 1
    for (int op = 0; op < 23; ++op) {
        const uint32_t cw  = PROG[op];
        const int u     = cw & 7;
        const int g     = (cw >> 3) & 7;
        const int initk = (cw >> 6) & 3;
        const int toB   = (cw >> 8) & 1;
        const int epik  = (cw >> 9) & 7;
        const int bid   = (cw >> 12) & 7;

        if (g) gwrite(g);

        if (initk == 1) {
            const float b0 = wsb[bid * 64 + m], b1 = wsb[bid * 64 + 32 + m];
#pragma unroll
            for (int i = 0; i < 16; ++i) { acc[0][i] = b0; acc[1][i] = b1; }
        } else if (initk == 2) {
#pragma unroll
            for (int i = 0; i < 16; ++i) { acc[0][i] = accB[0][i]; acc[1][i] = accB[1][i]; }
        } else if (initk == 3) {
            const float b0 = wsb[bid * 64 + m], b1 = wsb[bid * 64 + 32 + m];
#pragma unroll
            for (int i = 0; i < 16; ++i) { accB[0][i] = b0; accB[1][i] = b1; }
        }

        if (toB) ua(accB, u); else ua(acc, u);

        if (epik == 1)      epi_store(toB ? accB : acc, true);
        else if (epik == 2) epi_store(toB ? accB : acc, false);
        else if (epik == 4) epi_reduce(out + rowbase);
        else if (epik == 5) epi_reduce(out + BATCH + rowbase);
    }
}

extern "C" void kernel_launch(void* const* d_in, const int* in_sizes, int n_in,
                              void* d_out, int out_size, void* d_ws, size_t ws_size,
                              hipStream_t stream) {
    const int*   seq  = (const int*)  d_in[0];
    const int*   post = (const int*)  d_in[1];
    const int*   negt = (const int*)  d_in[2];
    const float* E    = (const float*)d_in[3];
    const float* tv   = (const float*)d_in[4];
    const float* nW1  = (const float*)d_in[5];
    const float* nb1  = (const float*)d_in[6];
    const float* nW2  = (const float*)d_in[7];
    const float* nb2  = (const float*)d_in[8];
    const float* aW1  = (const float*)d_in[9];
    const float* ab1  = (const float*)d_in[10];
    const float* aW2  = (const float*)d_in[11];
    const float* ab2  = (const float*)d_in[12];
    const float* oW1  = (const float*)d_in[13];
    const float* ob1  = (const float*)d_in[14];
    const float* oW2  = (const float*)d_in[15];
    const float* ob2  = (const float*)d_in[16];
    float* out = (float*)d_out;
    char*  ws  = (char*)d_ws;   // uses ~132.6 KB

    hipLaunchKernelGGL(prep_kernel, dim3(130), dim3(256), 0, stream,
                       tv, nW1, nW2, aW1, aW2, oW1, oW2,
                       nb1, nb2, ab1, ab2, ob1, ob2, ws);
    hipLaunchKernelGGL(logicnet_mfma, dim3(BATCH / 128), dim3(256), 0, stream,
                       seq, post, negt, E, tv, ws, out);
}

// Round 4
// 632.958 us; speedup vs baseline: 1.8063x; 1.8063x over previous
//
#include <hip/hip_runtime.h>
#include <stdint.h>
#include <math.h>

#define BATCH 131072
#define WS_TN_OFF 65536
#define WS_B_OFF  65544   // 6 x 64 floats: nb1,nb2,ab1,ab2,ob1,ob2

typedef __attribute__((ext_vector_type(8)))  short short8;   // 8 bf16
typedef __attribute__((ext_vector_type(16))) float float16;  // MFMA 32x32 acc

union S8 { short8 s; uint32_t u[4]; };
union F8 { float f[8]; uint32_t u[8]; float4 v4[2]; };

// ---------------- prep: weights -> bf16 (RNE) in B-frag order; biases + |tvec| ----------------
// B-frag for mfma_f32_32x32x16_bf16: lane n'=lane&31 -> n = nt*32+n'; k = kc*16 + (lane>>5)*8 + j.
// ws: u*8192 + (kc*2+nt)*1024 + lane*16 + j*2. units u: 0=nW1 1=nW2 2=aW1[0:64] 3=aW1[64:128]
// 4=aW2 5=oW1[0:64] 6=oW1[64:128] 7=oW2
__global__ __launch_bounds__(256)
void prep_kernel(const float* __restrict__ tvec,
                 const float* __restrict__ nW1, const float* __restrict__ nW2,
                 const float* __restrict__ aW1, const float* __restrict__ aW2,
                 const float* __restrict__ oW1, const float* __restrict__ oW2,
                 const float* __restrict__ nb1, const float* __restrict__ nb2,
                 const float* __restrict__ ab1, const float* __restrict__ ab2,
                 const float* __restrict__ ob1, const float* __restrict__ ob2,
                 char* __restrict__ ws)
{
    const int id = blockIdx.x * 256 + threadIdx.x;
    if (id == 0) {
        float s = 0.f;
        for (int j = 0; j < 64; ++j) s = fmaf(tvec[j], tvec[j], s);
        *(float*)(ws + WS_TN_OFF) = fmaxf(sqrtf(s), 1e-8f);
    }
    if (id < 32768) {
        const float* srcs[8] = { nW1, nW2, aW1, aW1 + 4096, aW2, oW1, oW1 + 4096, oW2 };
        const int u    = id >> 12;
        const int e    = id & 4095;
        const int j    = e & 7;
        const int lane = (e >> 3) & 63;
        const int f    = e >> 9;          // kc*2 + nt
        const int nt   = f & 1, kc = f >> 1;
        const int k    = kc * 16 + (lane >> 5) * 8 + j;
        const int n    = nt * 32 + (lane & 31);
        const uint32_t b = __float_as_uint(srcs[u][k * 64 + n]);
        // round-to-nearest-even bf16 (single-term W needs unbiased rounding)
        const uint32_t r = b + 0x7fffu + ((b >> 16) & 1u);
        ((uint16_t*)(ws + u * 8192 + f * 1024 + lane * 16))[j] = (uint16_t)(r >> 16);
    } else if (id < 33152) {
        const int b   = id - 32768;       // 0..383
        const int arr = b >> 6, j = b & 63;
        const float* bp = (arr == 0) ? nb1 : (arr == 1) ? nb2 : (arr == 2) ? ab1
                        : (arr == 3) ? ab2 : (arr == 4) ? ob1 : ob2;
        ((float*)(ws + WS_B_OFF))[b] = bp[j];
    }
}

// ---------------- main kernel: straight-line, A streamed from LDS, 2 acc banks ----------------
__global__ __launch_bounds__(256, 4)
void logicnet_mfma(const int* __restrict__ seq, const int* __restrict__ post,
                   const int* __restrict__ negt, const float* __restrict__ E,
                   const float* __restrict__ tvec,
                   const char* __restrict__ ws, float* __restrict__ out)
{
    __shared__ uint32_t lds[4 * 2112];     // per-wave slot: 32 rows x stride 66 (packed hi|lo)
    const int tid  = threadIdx.x;
    const int wid  = tid >> 6;
    const int lane = tid & 63;
    const int m    = lane & 31;            // batch row in tile / C col
    const int h    = lane >> 5;            // k-half / row-half selector
    const int rowbase = (blockIdx.x * 4 + wid) * 32;
    const int rr   = rowbase + m;
    uint32_t* const stage = &lds[wid * 2112];

    const float  tn  = *(const float*)(ws + WS_TN_OFF);
    const float* wsb = (const float*)(ws + WS_B_OFF);

    // preload biases (per-lane, constant-indexed later)
    float bv0[6], bv1[6];
#pragma unroll
    for (int b = 0; b < 6; ++b) { bv0[b] = wsb[b * 64 + m]; bv1[b] = wsb[b * 64 + 32 + m]; }

    const int s0 = seq[(size_t)rr * 5 + 0], s1i = seq[(size_t)rr * 5 + 1];
    const int s2 = seq[(size_t)rr * 5 + 2], s3 = seq[(size_t)rr * 5 + 3];
    const int s4 = seq[(size_t)rr * 5 + 4];
    const int ip = post[rr], im = negt[rr];

    float16 acc[2], accB[2];

    auto init = [&](float16 (&A)[2], int bid) {   // bid is a compile-time constant at each call
#pragma unroll
        for (int i = 0; i < 16; ++i) { A[0][i] = bv0[bid]; A[1][i] = bv1[bid]; }
    };
    auto copyBA = [&]() {
#pragma unroll
        for (int i = 0; i < 16; ++i) { acc[0][i] = accB[0][i]; acc[1][i] = accB[1][i]; }
    };

    // A += X(stage) @ W(unit u); X packed hi|lo in stage, W bf16 from ws. 16 MFMA.
    auto ua = [&](float16 (&A)[2], int u) {
        const char* wb = ws + u * 8192 + lane * 16;
#pragma unroll
        for (int kc = 0; kc < 4; ++kc) {
            const uint2* p2 = (const uint2*)&stage[m * 66 + kc * 16 + h * 8];
            uint2 a0 = p2[0], a1 = p2[1], a2 = p2[2], a3 = p2[3];
            S8 xhi, xlo;
            xhi.u[0] = (a0.x >> 16) | (a0.y & 0xffff0000u);
            xhi.u[1] = (a1.x >> 16) | (a1.y & 0xffff0000u);
            xhi.u[2] = (a2.x >> 16) | (a2.y & 0xffff0000u);
            xhi.u[3] = (a3.x >> 16) | (a3.y & 0xffff0000u);
            xlo.u[0] = (a0.x & 0xffffu) | (a0.y << 16);
            xlo.u[1] = (a1.x & 0xffffu) | (a1.y << 16);
            xlo.u[2] = (a2.x & 0xffffu) | (a2.y << 16);
            xlo.u[3] = (a3.x & 0xffffu) | (a3.y << 16);
#pragma unroll
            for (int nt = 0; nt < 2; ++nt) {
                short8 whi = *(const short8*)(wb + (kc * 2 + nt) * 1024);
                A[nt] = __builtin_amdgcn_mfma_f32_32x32x16_bf16(xhi.s, whi, A[nt], 0, 0, 0);
                A[nt] = __builtin_amdgcn_mfma_f32_32x32x16_bf16(xlo.s, whi, A[nt], 0, 0, 0);
            }
        }
    };

    // C-layout -> packed hi|lo into stage (optionally leaky-relu)
    auto epi = [&](const float16 (&A)[2], bool act) {
#pragma unroll
        for (int nt = 0; nt < 2; ++nt) {
            const int c = nt * 32 + m;
#pragma unroll
            for (int g = 0; g < 4; ++g)
#pragma unroll
                for (int q = 0; q < 4; ++q) {
                    const int r = q + 8 * g + 4 * h;
                    float v = A[nt][g * 4 + q];
                    if (act) v = fmaxf(v, 0.01f * v);
                    const uint32_t uu = __float_as_uint(v);
                    const uint32_t hb = uu & 0xffff0000u;
                    const uint32_t lo = __float_as_uint(v - __uint_as_float(hb));
                    stage[r * 66 + c] = hb | (lo >> 16);
                }
        }
    };

    // embedding gather -> stage (packed hi|lo)
    auto gw = [&](int idx) {
        const float4* e = (const float4*)(E + (size_t)idx * 64 + h * 8);
#pragma unroll
        for (int kc = 0; kc < 4; ++kc) {
            F8 xf8;
            xf8.v4[0] = e[kc * 4];
            xf8.v4[1] = e[kc * 4 + 1];
            uint32_t pk[8];
#pragma unroll
            for (int i = 0; i < 8; ++i) {
                const uint32_t b  = xf8.u[i];
                const uint32_t hb = b & 0xffff0000u;
                const uint32_t lo = __float_as_uint(xf8.f[i] - __uint_as_float(hb));
                pk[i] = hb | (lo >> 16);
            }
            uint2* q = (uint2*)&stage[m * 66 + kc * 16 + h * 8];
            q[0] = make_uint2(pk[0], pk[1]);
            q[1] = make_uint2(pk[2], pk[3]);
            q[2] = make_uint2(pk[4], pk[5]);
            q[3] = make_uint2(pk[6], pk[7]);
        }
    };

    auto reduce = [&](float* outp) {
#pragma unroll
        for (int nt = 0; nt < 2; ++nt) {
            const int c = nt * 32 + m;
#pragma unroll
            for (int g = 0; g < 4; ++g)
#pragma unroll
                for (int q = 0; q < 4; ++q) {
                    const int r = q + 8 * g + 4 * h;
                    stage[r * 66 + c] = __float_as_uint(acc[nt][g * 4 + q]);
                }
        }
        float num = 0.f, ss = 0.f;
        const float* tp = tvec + h * 32;
        const uint32_t* xp = &stage[m * 66 + h * 32];
#pragma unroll
        for (int i = 0; i < 32; i += 2) {
            const float x0 = __uint_as_float(xp[i]);
            const float x1 = __uint_as_float(xp[i + 1]);
            num = fmaf(x0, tp[i], fmaf(x1, tp[i + 1], num));
            ss  = fmaf(x0, x0, fmaf(x1, x1, ss));
        }
        num += __shfl_xor(num, 32, 64);
        ss  += __shfl_xor(ss, 32, 64);
        if (h == 0) outp[m] = num / (fmaxf(sqrtf(ss), 1e-8f) * tn) * 10.0f;
    };

    // -------- the 23-pass program (straight-line; per-wave LDS ops are in-order) --------
    // bias ids: 0=nb1 1=nb2 2=ab1 3=ab2 4=ob1 5=ob2
    gw(s1i); init(acc, 0); ua(acc, 0); epi(acc, true);    // n1 hidden
    init(acc, 1); ua(acc, 1); epi(acc, false);            // S0 = n1
    init(acc, 2); ua(acc, 3);                             // ab1 + aW1[64:] @ n1
    gw(s0); ua(acc, 2); epi(acc, true);                   // += aW1[0:] @ e0
    init(acc, 3); ua(acc, 4); epi(acc, false);            // S0 = i5
    init(accB, 2); ua(accB, 2);                           // accB = ab1 + aW1[0:] @ i5
    gw(s2); init(acc, 4); ua(acc, 5);                     // ob1 + oW1[0:] @ e2
    gw(s3); ua(acc, 6); epi(acc, true);                   // += oW1[64:] @ e3
    init(acc, 5); ua(acc, 7); epi(acc, false);            // S0 = i6
    ua(accB, 3); epi(accB, true);                         // accB += aW1[64:] @ i6 -> S0 = h(i7)
    init(acc, 3); ua(acc, 4); epi(acc, false);            // S0 = i7
    init(acc, 0); ua(acc, 0); epi(acc, true);             // n7 hidden
    init(acc, 1); ua(acc, 1); epi(acc, false);            // S0 = n7
    init(acc, 4); ua(acc, 5);                             // ob1 + oW1[0:] @ n7
    gw(s4); ua(acc, 6); epi(acc, true);                   // += oW1[64:] @ e4
    init(acc, 5); ua(acc, 7); epi(acc, false);            // S0 = out8
    init(acc, 0); ua(acc, 0); epi(acc, true);             // enc hidden
    init(acc, 1); ua(acc, 1); epi(acc, false);            // S0 = enc
    init(accB, 4); ua(accB, 5);                           // accB = ob1 + oW1[0:] @ enc
    gw(ip); copyBA(); ua(acc, 6); epi(acc, true);         // pos hidden
    init(acc, 5); ua(acc, 7); reduce(out + rowbase);      // pos out
    gw(im); copyBA(); ua(acc, 6); epi(acc, true);         // neg hidden
    init(acc, 5); ua(acc, 7); reduce(out + BATCH + rowbase); // neg out
}

extern "C" void kernel_launch(void* const* d_in, const int* in_sizes, int n_in,
                              void* d_out, int out_size, void* d_ws, size_t ws_size,
                              hipStream_t stream) {
    const int*   seq  = (const int*)  d_in[0];
    const int*   post = (const int*)  d_in[1];
    const int*   negt = (const int*)  d_in[2];
    const float* E    = (const float*)d_in[3];
    const float* tv   = (const float*)d_in[4];
    const float* nW1  = (const float*)d_in[5];
    const float* nb1  = (const float*)d_in[6];
    const float* nW2  = (const float*)d_in[7];
    const float* nb2  = (const float*)d_in[8];
    const float* aW1  = (const float*)d_in[9];
    const float* ab1  = (const float*)d_in[10];
    const float* aW2  = (const float*)d_in[11];
    const float* ab2  = (const float*)d_in[12];
    const float* oW1  = (const float*)d_in[13];
    const float* ob1  = (const float*)d_in[14];
    const float* oW2  = (const float*)d_in[15];
    const float* ob2  = (const float*)d_in[16];
    float* out = (float*)d_out;
    char*  ws  = (char*)d_ws;   // uses ~67 KB

    hipLaunchKernelGGL(prep_kernel, dim3(130), dim3(256), 0, stream,
                       tv, nW1, nW2, aW1, aW2, oW1, oW2,
                       nb1, nb2, ab1, ab2, ob1, ob2, ws);
    hipLaunchKernelGGL(logicnet_mfma, dim3(BATCH / 128), dim3(256), 0, stream,
                       seq, post, negt, E, tv, ws, out);
}

// Round 5
// 412.214 us; speedup vs baseline: 2.7736x; 1.5355x over previous
//
#include <hip/hip_runtime.h>
#include <stdint.h>
#include <math.h>

#define BATCH 131072
#define WS_TN_OFF 65536
#define WS_B_OFF  65544   // 6 x 64 floats: nb1,nb2,ab1,ab2,ob1,ob2

typedef __attribute__((ext_vector_type(8)))  short short8;   // 8 bf16
typedef __attribute__((ext_vector_type(16))) float float16;  // MFMA 32x32 acc

union S8 { short8 s; uint32_t u[4]; };
union F8 { float f[8]; uint32_t u[8]; float4 v4[2]; };

// ---------------- prep: weights -> bf16 (RNE) in B-frag order; biases + |tvec| ----------------
// B-frag for mfma_f32_32x32x16_bf16: lane n'=lane&31 -> n = nt*32+n'; k = kc*16 + (lane>>5)*8 + j.
// ws: u*8192 + (kc*2+nt)*1024 + lane*16 + j*2. units u: 0=nW1 1=nW2 2=aW1[0:64] 3=aW1[64:128]
// 4=aW2 5=oW1[0:64] 6=oW1[64:128] 7=oW2
__global__ __launch_bounds__(256)
void prep_kernel(const float* __restrict__ tvec,
                 const float* __restrict__ nW1, const float* __restrict__ nW2,
                 const float* __restrict__ aW1, const float* __restrict__ aW2,
                 const float* __restrict__ oW1, const float* __restrict__ oW2,
                 const float* __restrict__ nb1, const float* __restrict__ nb2,
                 const float* __restrict__ ab1, const float* __restrict__ ab2,
                 const float* __restrict__ ob1, const float* __restrict__ ob2,
                 char* __restrict__ ws)
{
    const int id = blockIdx.x * 256 + threadIdx.x;
    if (id == 0) {
        float s = 0.f;
        for (int j = 0; j < 64; ++j) s = fmaf(tvec[j], tvec[j], s);
        *(float*)(ws + WS_TN_OFF) = fmaxf(sqrtf(s), 1e-8f);
    }
    if (id < 32768) {
        const float* srcs[8] = { nW1, nW2, aW1, aW1 + 4096, aW2, oW1, oW1 + 4096, oW2 };
        const int u    = id >> 12;
        const int e    = id & 4095;
        const int j    = e & 7;
        const int lane = (e >> 3) & 63;
        const int f    = e >> 9;          // kc*2 + nt
        const int nt   = f & 1, kc = f >> 1;
        const int k    = kc * 16 + (lane >> 5) * 8 + j;
        const int n    = nt * 32 + (lane & 31);
        const uint32_t b = __float_as_uint(srcs[u][k * 64 + n]);
        const uint32_t r = b + 0x7fffu + ((b >> 16) & 1u);   // RNE to bf16
        ((uint16_t*)(ws + u * 8192 + f * 1024 + lane * 16))[j] = (uint16_t)(r >> 16);
    } else if (id < 33152) {
        const int b   = id - 32768;       // 0..383
        const int arr = b >> 6, j = b & 63;
        const float* bp = (arr == 0) ? nb1 : (arr == 1) ? nb2 : (arr == 2) ? ab1
                        : (arr == 3) ? ab2 : (arr == 4) ? ob1 : ob2;
        ((float*)(ws + WS_B_OFF))[b] = bp[j];
    }
}

// ---------------- main kernel: micro-coded 24-op program, ONE acc bank ----------------
// op word: g(0:2) | u(3:5) | sH(6) | init(7) | bid(8:10) | epi(11:12) | red(13:14)
// g: 0 none, 1..5 seq[:,g-1], 6 pos_target, 7 neg_target  (gather -> S0)
// sH: ua reads S1 (bf16 hi-only, 8 MFMA) instead of S0 (packed hi|lo, 16 MFMA)
// epi: 0 none, 1 act->S0, 2 raw->S0, 3 raw->S1(bf16 RNE)
// red: 0 none, 1 reduce->out[pos], 2 reduce->out[neg]
#define OPW(g,u,sH,ini,bid,ep,rd) ((g)|((u)<<3)|((sH)<<6)|((ini)<<7)|((bid)<<8)|((ep)<<11)|((rd)<<13))

__global__ __launch_bounds__(256, 3)
void logicnet_mfma(const int* __restrict__ seq, const int* __restrict__ post,
                   const int* __restrict__ negt, const float* __restrict__ E,
                   const char* __restrict__ ws, float* __restrict__ out)
{
    static const uint32_t PROG[24] = {
        OPW(3,5,0,1,4,0,0),  //  1: acc=ob1 + oW1[0:]@gather(s2)
        OPW(4,6,0,0,0,1,0),  //  2: += oW1[64:]@gather(s3), act -> S0 = h(i6)
        OPW(0,7,0,1,5,3,0),  //  3: acc=ob2 + oW2@S0, raw -> S1 = i6
        OPW(2,0,0,1,0,1,0),  //  4: acc=nb1 + nW1@gather(s1), act -> S0
        OPW(0,1,0,1,1,2,0),  //  5: acc=nb2 + nW2@S0, raw -> S0 = n1
        OPW(0,3,0,1,2,0,0),  //  6: acc=ab1 + aW1[64:]@n1
        OPW(1,2,0,0,0,1,0),  //  7: += aW1[0:]@gather(s0), act -> S0 = h(i5)
        OPW(0,4,0,1,3,2,0),  //  8: acc=ab2 + aW2@S0, raw -> S0 = i5
        OPW(0,2,0,1,2,0,0),  //  9: acc=ab1 + aW1[0:]@i5
        OPW(0,3,1,0,0,1,0),  // 10: += aW1[64:]@S1(i6), act -> S0 = h(i7)
        OPW(0,4,0,1,3,2,0),  // 11: acc=ab2 + aW2@S0, raw -> S0 = i7
        OPW(0,0,0,1,0,1,0),  // 12: acc=nb1 + nW1@S0, act
        OPW(0,1,0,1,1,2,0),  // 13: acc=nb2 + nW2@S0, raw -> S0 = n7
        OPW(0,5,0,1,4,0,0),  // 14: acc=ob1 + oW1[0:]@n7
        OPW(5,6,0,0,0,1,0),  // 15: += oW1[64:]@gather(s4), act -> S0 = h(out8)
        OPW(0,7,0,1,5,2,0),  // 16: acc=ob2 + oW2@S0, raw -> S0 = out8
        OPW(0,0,0,1,0,1,0),  // 17: acc=nb1 + nW1@S0, act
        OPW(0,1,0,1,1,3,0),  // 18: acc=nb2 + nW2@S0, raw -> S1 = enc
        OPW(0,5,1,1,4,0,0),  // 19: acc=ob1 + oW1[0:]@S1(enc)
        OPW(6,6,0,0,0,1,0),  // 20: += oW1[64:]@gather(ip), act -> S0
        OPW(0,7,0,1,5,0,1),  // 21: acc=ob2 + oW2@S0, reduce -> out(pos)
        OPW(0,5,1,1,4,0,0),  // 22: acc=ob1 + oW1[0:]@S1(enc)  (recompute)
        OPW(7,6,0,0,0,1,0),  // 23: += oW1[64:]@gather(im), act -> S0
        OPW(0,7,0,1,5,0,2),  // 24: acc=ob2 + oW2@S0, reduce -> out(neg)
    };

    // per-wave: S0 = 2112 u32 (stride 66, packed hi|lo), S1 = 1088 u32 (stride 34, bf16)
    // block-shared tail: 384 u32 biases + 64 u32 tvec
    __shared__ uint32_t lds[4 * 3200 + 448];
    const int tid  = threadIdx.x;
    const int wid  = tid >> 6;
    const int lane = tid & 63;
    const int m    = lane & 31;            // batch row in tile / C col
    const int h    = lane >> 5;            // k-half / row-half selector
    const int rowbase = (blockIdx.x * 4 + wid) * 32;
    const int rr   = rowbase + m;
    uint32_t* const S0 = &lds[wid * 3200];
    uint32_t* const S1 = S0 + 2112;
    float*    const ldsb = (float*)&lds[12800];   // biases [6][64]
    float*    const ltv  = (float*)&lds[13184];   // tvec [64]

    {   // stage biases + tvec into block-shared LDS (one barrier, start only)
        const uint32_t* wsb32 = (const uint32_t*)(ws + WS_B_OFF);
        const uint32_t* tv32  = (const uint32_t*)(ws + WS_B_OFF) - 2; // unused, placeholder
        (void)tv32;
        for (int t = tid; t < 384; t += 256) lds[12800 + t] = wsb32[t];
    }
    // tvec comes from E's neighbor input; load via kernel arg trick below
    // (tvec pointer passed through ws? no — passed as separate arg removed; reuse: see launch)
    // NOTE: tvec staged by the extra arg-free path: biases cover 384; tvec loaded from ws tail.
    {
        const uint32_t* tvsrc = (const uint32_t*)(ws + WS_B_OFF + 1536); // prep stores tvec here
        for (int t = tid; t < 64; t += 256) lds[13184 + t] = tvsrc[t];
    }
    __syncthreads();

    const float tn = *(const float*)(ws + WS_TN_OFF);

    const int sv0 = seq[(size_t)rr * 5 + 0], sv1 = seq[(size_t)rr * 5 + 1];
    const int sv2 = seq[(size_t)rr * 5 + 2], sv3 = seq[(size_t)rr * 5 + 3];
    const int sv4 = seq[(size_t)rr * 5 + 4];
    const int ipv = post[rr], imv = negt[rr];

    float16 acc[2];

    // embedding gather -> S0 (packed hi|lo)
    auto gw = [&](int idx) {
        const float4* e = (const float4*)(E + (size_t)idx * 64 + h * 8);
#pragma unroll
        for (int kc = 0; kc < 4; ++kc) {
            F8 xf8;
            xf8.v4[0] = e[kc * 4];
            xf8.v4[1] = e[kc * 4 + 1];
            uint32_t pk[8];
#pragma unroll
            for (int i = 0; i < 8; ++i) {
                const uint32_t b  = xf8.u[i];
                const uint32_t hb = b & 0xffff0000u;
                const uint32_t lo = __float_as_uint(xf8.f[i] - __uint_as_float(hb));
                pk[i] = hb | (lo >> 16);
            }
            uint2* q = (uint2*)&S0[m * 66 + kc * 16 + h * 8];
            q[0] = make_uint2(pk[0], pk[1]);
            q[1] = make_uint2(pk[2], pk[3]);
            q[2] = make_uint2(pk[4], pk[5]);
            q[3] = make_uint2(pk[6], pk[7]);
        }
    };

    // acc += X(S0 packed) @ W(unit u): 16 MFMA
    auto uaP = [&](int u) {
        const char* wb = ws + u * 8192 + lane * 16;
#pragma unroll
        for (int kc = 0; kc < 4; ++kc) {
            const uint2* p2 = (const uint2*)&S0[m * 66 + kc * 16 + h * 8];
            uint2 a0 = p2[0], a1 = p2[1], a2 = p2[2], a3 = p2[3];
            S8 xhi, xlo;
            xhi.u[0] = (a0.x >> 16) | (a0.y & 0xffff0000u);
            xhi.u[1] = (a1.x >> 16) | (a1.y & 0xffff0000u);
            xhi.u[2] = (a2.x >> 16) | (a2.y & 0xffff0000u);
            xhi.u[3] = (a3.x >> 16) | (a3.y & 0xffff0000u);
            xlo.u[0] = (a0.x & 0xffffu) | (a0.y << 16);
            xlo.u[1] = (a1.x & 0xffffu) | (a1.y << 16);
            xlo.u[2] = (a2.x & 0xffffu) | (a2.y << 16);
            xlo.u[3] = (a3.x & 0xffffu) | (a3.y << 16);
#pragma unroll
            for (int nt = 0; nt < 2; ++nt) {
                short8 whi = *(const short8*)(wb + (kc * 2 + nt) * 1024);
                acc[nt] = __builtin_amdgcn_mfma_f32_32x32x16_bf16(xhi.s, whi, acc[nt], 0, 0, 0);
                acc[nt] = __builtin_amdgcn_mfma_f32_32x32x16_bf16(xlo.s, whi, acc[nt], 0, 0, 0);
            }
        }
    };

    // acc += X(S1 bf16) @ W(unit u): 8 MFMA
    auto uaH = [&](int u) {
        const char* wb = ws + u * 8192 + lane * 16;
#pragma unroll
        for (int kc = 0; kc < 4; ++kc) {
            const uint2* p2 = (const uint2*)&S1[m * 34 + kc * 8 + h * 4];
            uint2 a0 = p2[0], a1 = p2[1];
            S8 xhi;
            xhi.u[0] = a0.x; xhi.u[1] = a0.y; xhi.u[2] = a1.x; xhi.u[3] = a1.y;
#pragma unroll
            for (int nt = 0; nt < 2; ++nt) {
                short8 whi = *(const short8*)(wb + (kc * 2 + nt) * 1024);
                acc[nt] = __builtin_amdgcn_mfma_f32_32x32x16_bf16(xhi.s, whi, acc[nt], 0, 0, 0);
            }
        }
    };

    // C-layout -> packed hi|lo into S0 (optional leaky-relu)
    auto epiS0 = [&](bool act) {
#pragma unroll
        for (int nt = 0; nt < 2; ++nt) {
            const int c = nt * 32 + m;
#pragma unroll
            for (int g2 = 0; g2 < 4; ++g2)
#pragma unroll
                for (int q = 0; q < 4; ++q) {
                    const int r = q + 8 * g2 + 4 * h;
                    float v = acc[nt][g2 * 4 + q];
                    if (act) v = fmaxf(v, 0.01f * v);
                    const uint32_t uu = __float_as_uint(v);
                    const uint32_t hb = uu & 0xffff0000u;
                    const uint32_t lo = __float_as_uint(v - __uint_as_float(hb));
                    S0[r * 66 + c] = hb | (lo >> 16);
                }
        }
    };

    // C-layout -> bf16 RNE into S1 (raw)
    auto epiS1 = [&]() {
        uint16_t* p = (uint16_t*)S1;
#pragma unroll
        for (int nt = 0; nt < 2; ++nt) {
            const int c = nt * 32 + m;
#pragma unroll
            for (int g2 = 0; g2 < 4; ++g2)
#pragma unroll
                for (int q = 0; q < 4; ++q) {
                    const int r = q + 8 * g2 + 4 * h;
                    const uint32_t b = __float_as_uint(acc[nt][g2 * 4 + q]);
                    const uint32_t rn = b + 0x7fffu + ((b >> 16) & 1u);
                    p[r * 68 + c] = (uint16_t)(rn >> 16);
                }
        }
    };

    auto reduce = [&](float* outp) {
#pragma unroll
        for (int nt = 0; nt < 2; ++nt) {
            const int c = nt * 32 + m;
#pragma unroll
            for (int g2 = 0; g2 < 4; ++g2)
#pragma unroll
                for (int q = 0; q < 4; ++q) {
                    const int r = q + 8 * g2 + 4 * h;
                    S0[r * 66 + c] = __float_as_uint(acc[nt][g2 * 4 + q]);
                }
        }
        float num = 0.f, ss = 0.f;
        const float* tp = ltv + h * 32;
        const uint32_t* xp = &S0[m * 66 + h * 32];
#pragma unroll
        for (int i = 0; i < 32; i += 2) {
            const float x0 = __uint_as_float(xp[i]);
            const float x1 = __uint_as_float(xp[i + 1]);
            num = fmaf(x0, tp[i], fmaf(x1, tp[i + 1], num));
            ss  = fmaf(x0, x0, fmaf(x1, x1, ss));
        }
        num += __shfl_xor(num, 32, 64);
        ss  += __shfl_xor(ss, 32, 64);
        if (h == 0) outp[m] = num / (fmaxf(sqrtf(ss), 1e-8f) * tn) * 10.0f;
    };

#pragma unroll 1
    for (int op = 0; op < 24; ++op) {
        const uint32_t cw = PROG[op];
        const int g   = cw & 7;
        const int u   = (cw >> 3) & 7;
        const int sH  = (cw >> 6) & 1;
        const int ini = (cw >> 7) & 1;
        const int bid = (cw >> 8) & 7;
        const int ep  = (cw >> 11) & 3;
        const int rd  = (cw >> 13) & 3;

        if (g) {
            int idx;
            switch (g) {
                case 1: idx = sv0; break;
                case 2: idx = sv1; break;
                case 3: idx = sv2; break;
                case 4: idx = sv3; break;
                case 5: idx = sv4; break;
                case 6: idx = ipv; break;
                default: idx = imv; break;
            }
            gw(idx);
        }
        if (ini) {
            const float b0 = ldsb[bid * 64 + m], b1 = ldsb[bid * 64 + 32 + m];
#pragma unroll
            for (int i = 0; i < 16; ++i) { acc[0][i] = b0; acc[1][i] = b1; }
        }
        if (sH) uaH(u); else uaP(u);

        if (ep == 1)      epiS0(true);
        else if (ep == 2) epiS0(false);
        else if (ep == 3) epiS1();

        if (rd == 1)      reduce(out + rowbase);
        else if (rd == 2) reduce(out + BATCH + rowbase);
    }
}

// small helper to copy tvec (fp32) into ws tail so the main kernel can stage it to LDS
__global__ __launch_bounds__(64)
void tvec_copy(const float* __restrict__ tvec, char* __restrict__ ws) {
    const int t = threadIdx.x;
    ((float*)(ws + WS_B_OFF + 1536))[t] = tvec[t];
}

extern "C" void kernel_launch(void* const* d_in, const int* in_sizes, int n_in,
                              void* d_out, int out_size, void* d_ws, size_t ws_size,
                              hipStream_t stream) {
    const int*   seq  = (const int*)  d_in[0];
    const int*   post = (const int*)  d_in[1];
    const int*   negt = (const int*)  d_in[2];
    const float* E    = (const float*)d_in[3];
    const float* tv   = (const float*)d_in[4];
    const float* nW1  = (const float*)d_in[5];
    const float* nb1  = (const float*)d_in[6];
    const float* nW2  = (const float*)d_in[7];
    const float* nb2  = (const float*)d_in[8];
    const float* aW1  = (const float*)d_in[9];
    const float* ab1  = (const float*)d_in[10];
    const float* aW2  = (const float*)d_in[11];
    const float* ab2  = (const float*)d_in[12];
    const float* oW1  = (const float*)d_in[13];
    const float* ob1  = (const float*)d_in[14];
    const float* oW2  = (const float*)d_in[15];
    const float* ob2  = (const float*)d_in[16];
    float* out = (float*)d_out;
    char*  ws  = (char*)d_ws;   // uses ~67.3 KB

    hipLaunchKernelGGL(prep_kernel, dim3(130), dim3(256), 0, stream,
                       tv, nW1, nW2, aW1, aW2, oW1, oW2,
                       nb1, nb2, ab1, ab2, ob1, ob2, ws);
    hipLaunchKernelGGL(tvec_copy, dim3(1), dim3(64), 0, stream, tv, ws);
    hipLaunchKernelGGL(logicnet_mfma, dim3(BATCH / 128), dim3(256), 0, stream,
                       seq, post, negt, E, ws, out);
}